// Round 4
// baseline (334.082 us; speedup 1.0000x reference)
//
#include <hip/hip_runtime.h>
#include <hip/hip_bf16.h>

using bf16_t = __bf16;
using bf16x8 = __attribute__((ext_vector_type(8))) __bf16;
using bf16x4 = __attribute__((ext_vector_type(4))) __bf16;
using bf16x2 = __attribute__((ext_vector_type(2))) __bf16;
using f32x4  = __attribute__((ext_vector_type(4))) float;

#define S_  2048
#define D_  1024

typedef __attribute__((address_space(1))) unsigned int glb_u32;
typedef __attribute__((address_space(3))) unsigned int lds_u32;

__device__ __forceinline__ void async_cp16(const void* g, void* lds) {
    __builtin_amdgcn_global_load_lds(
        (glb_u32*)(unsigned long long)g,
        (lds_u32*)(unsigned int)(unsigned long long)lds,
        16, 0, 0);
}

// ---------------- weights f32 -> bf16 ----------------
__global__ __launch_bounds__(256) void cast4_f32_bf16(const float* __restrict__ a, const float* __restrict__ b,
                                                      const float* __restrict__ c, const float* __restrict__ dd,
                                                      bf16_t* __restrict__ oa, bf16_t* __restrict__ ob,
                                                      bf16_t* __restrict__ oc, bf16_t* __restrict__ od, int n4) {
    int i = blockIdx.x * 256 + threadIdx.x;
    if (i >= n4) return;
    const float* s; bf16_t* d;
    int w = blockIdx.y;
    if      (w == 0) { s = a;  d = oa; }
    else if (w == 1) { s = b;  d = ob; }
    else if (w == 2) { s = c;  d = oc; }
    else             { s = dd; d = od; }
    float4 f = reinterpret_cast<const float4*>(s)[i];
    bf16x4 o;
    o[0] = (bf16_t)f.x; o[1] = (bf16_t)f.y; o[2] = (bf16_t)f.z; o[3] = (bf16_t)f.w;
    reinterpret_cast<bf16x4*>(d)[i] = o;
}

// ---------------- ring GEMM: C[M x 1024] = A[M x 1024] * W[1024 x 1024]^T ----------------
// 3-stage LDS ring, counted vmcnt, raw s_barrier -- stage(i+1)'s loads stay in
// flight ACROSS the barrier (never vmcnt(0) in the loop). No ds_writes at all:
// both operands staged by global_load_lds. Ring safety: iter i issues stage(i+2)
// AFTER the barrier, overwriting buffer (i-1)%3 which all waves finished reading.
// MODE 0 (QKV): A is f32, read directly via global_load_lds into a f32 LDS tile
//   (8 slots/row, full XOR swizzle -> conflict-free); cvt->bf16 at frag read on
//   the idle VALU. z in {0,1,2} from blockIdx: Q (x cs), K, V (per-head V^T with
//   s pre-permuted to MFMA A-frag order: pos = q*8 + hi*4 + r).
// MODE 1 (out): A bf16 (attn output), C f32.
// Tile 128x128, 4 waves, wave-tile 64x64. LDS: MODE0 72KB -> 2 WG/CU,
// MODE1 48KB -> 3 WG/CU. XCD-banded grid: bid&7 = XCD, 8 m-blocks per band.
template <int MODE>
__global__ __launch_bounds__(256) void gemm_ring(const float* __restrict__ qf,
                                                 const float* __restrict__ kf,
                                                 const float* __restrict__ vf,
                                                 const bf16_t* __restrict__ Wq,
                                                 const bf16_t* __restrict__ Wk,
                                                 const bf16_t* __restrict__ Wv,
                                                 bf16_t* __restrict__ Qp,
                                                 bf16_t* __restrict__ Kp,
                                                 bf16_t* __restrict__ Vt,
                                                 float cs,
                                                 const bf16_t* __restrict__ Ab,
                                                 const bf16_t* __restrict__ Wo,
                                                 float* __restrict__ Co) {
    constexpr int AE = (MODE == 0) ? 2 : 1;            // A elems are 2 bf16-units wide if f32
    __shared__ bf16_t As[3 * 128 * 32 * AE];           // per-stage: 8192*AE/2 ... MODE0 16KB, MODE1 8KB
    __shared__ bf16_t Bs[3 * 128 * 32];                // per-stage 8KB
    const int K = 1024;
    int tid  = threadIdx.x;
    int lane = tid & 63;
    int w    = tid >> 6;
    int l15  = lane & 15, quad = lane >> 4;
    int wm = (w >> 1) * 64, wn = (w & 1) * 64;

    // ---- decode: XCD-banded; MODE0 adds z (3 GEMMs in one dispatch) ----
    int bid = blockIdx.x;
    int xcd = bid & 7, rem = bid >> 3;
    int z = 0, r2 = rem;
    if (MODE == 0) { z = rem >> 6; r2 = rem & 63; }
    int m0 = (xcd * 8 + (r2 & 7)) * 128;
    int n0 = (r2 >> 3) * 128;

    const float*  Af = nullptr; const bf16_t* Ab16 = nullptr; const bf16_t* Bt;
    if (MODE == 0) {
        if      (z == 0) { Af = qf; Bt = Wq; }
        else if (z == 1) { Af = kf; Bt = Wk; }
        else             { Af = vf; Bt = Wv; }
    } else { Ab16 = Ab; Bt = Wo; }

    // ---- per-thread staging addresses (XOR source swizzle baked in) ----
    // A (MODE0, f32): tile 128x32 f32 = 1024 x 16B chunks; 4 per thread.
    // A (MODE1, bf16): tile 128x32 = 512 chunks; 2 per thread.
    // B (bf16): 512 chunks; 2 per thread.
    const float*  aSrcF[4]; bf16_t* aDstF[4];
    const bf16_t* aSrcH[2]; bf16_t* aDstH[2];
    const bf16_t* bSrc[2];  bf16_t* bDst[2];
    if (MODE == 0) {
#pragma unroll
        for (int j = 0; j < 4; j++) {
            int linear = j * 256 + tid;
            int row = linear >> 3, s = linear & 7;
            aSrcF[j] = Af + (size_t)(m0 + row) * K + (s ^ (row & 7)) * 4;
            aDstF[j] = As + linear * 8;                 // 16B chunk = 8 bf16 units
        }
    } else {
#pragma unroll
        for (int j = 0; j < 2; j++) {
            int linear = j * 256 + tid;
            int row = linear >> 2, s = linear & 3;
            aSrcH[j] = Ab16 + (size_t)(m0 + row) * K + (s ^ (row & 3)) * 8;
            aDstH[j] = As + linear * 8;
        }
    }
#pragma unroll
    for (int j = 0; j < 2; j++) {
        int linear = j * 256 + tid;
        int row = linear >> 2, s = linear & 3;
        bSrc[j] = Bt + (size_t)(n0 + row) * K + (s ^ (row & 3)) * 8;
        bDst[j] = Bs + linear * 8;
    }

    constexpr int ASTG = (MODE == 0) ? 8192 : 4096;     // bf16-units per A stage
    auto stage = [&](int buf, int koff) {
        if (MODE == 0) {
#pragma unroll
            for (int j = 0; j < 4; j++) async_cp16(aSrcF[j] + koff, aDstF[j] + buf * ASTG);
        } else {
#pragma unroll
            for (int j = 0; j < 2; j++) async_cp16(aSrcH[j] + koff, aDstH[j] + buf * ASTG);
        }
#pragma unroll
        for (int j = 0; j < 2; j++) async_cp16(bSrc[j] + koff, bDst[j] + buf * 4096);
    };

    f32x4 acc[4][4] = {};

    stage(0, 0);
    stage(1, 32);

    int cur = 0, nx2 = 2;
    for (int i = 0; i < 32; ++i) {
        // wait own stage(i) loads; leave stage(i+1)'s in flight across the barrier
        if (i == 31) {
            asm volatile("s_waitcnt vmcnt(0)" ::: "memory");
        } else if (MODE == 0) {
            asm volatile("s_waitcnt vmcnt(6)" ::: "memory");
        } else {
            asm volatile("s_waitcnt vmcnt(4)" ::: "memory");
        }
        __builtin_amdgcn_s_barrier();      // all waves' stage(i) landed; buffer (i-1)%3 fully consumed
        if (i + 2 < 32) stage(nx2, (i + 2) * 32);

        // ---- fragments from buf[cur] ----
        bf16x8 af[4], bfr[4];
        if (MODE == 0) {
            const float* AsF = reinterpret_cast<const float*>(As) + cur * 4096;
#pragma unroll
            for (int mt = 0; mt < 4; mt++) {
                int row = wm + mt * 16 + l15, r7 = row & 7;
                f32x4 v0 = *reinterpret_cast<const f32x4*>(&AsF[row * 32 + ((2 * quad)     ^ r7) * 4]);
                f32x4 v1 = *reinterpret_cast<const f32x4*>(&AsF[row * 32 + ((2 * quad + 1) ^ r7) * 4]);
#pragma unroll
                for (int j = 0; j < 4; j++) { af[mt][j] = (bf16_t)v0[j]; af[mt][4 + j] = (bf16_t)v1[j]; }
            }
        } else {
            const bf16_t* AsH = As + cur * 4096;
#pragma unroll
            for (int mt = 0; mt < 4; mt++) {
                int row = wm + mt * 16 + l15;
                af[mt] = *reinterpret_cast<const bf16x8*>(&AsH[row * 32 + (quad ^ (row & 3)) * 8]);
            }
        }
        const bf16_t* Bsb = Bs + cur * 4096;
#pragma unroll
        for (int nt = 0; nt < 4; nt++) {
            int row = wn + nt * 16 + l15;
            bfr[nt] = *reinterpret_cast<const bf16x8*>(&Bsb[row * 32 + (quad ^ (row & 3)) * 8]);
        }
#pragma unroll
        for (int mt = 0; mt < 4; mt++)
#pragma unroll
            for (int nt = 0; nt < 4; nt++)
                acc[mt][nt] = __builtin_amdgcn_mfma_f32_16x16x32_bf16(af[mt], bfr[nt], acc[mt][nt], 0, 0, 0);

        cur = (cur == 2) ? 0 : cur + 1;
        nx2 = (nx2 == 2) ? 0 : nx2 + 1;
    }

    // ---- epilogue ----
    if (MODE == 0 && z == 2) {
#pragma unroll
        for (int mt = 0; mt < 4; mt++)
#pragma unroll
            for (int nt = 0; nt < 4; nt++) {
                int m = m0 + wm + mt * 16 + quad * 4;   // s-dim base (4 consecutive)
                int n = n0 + wn + nt * 16 + l15;        // d-dim
                bf16x4 o4;
#pragma unroll
                for (int r = 0; r < 4; r++) o4[r] = (bf16_t)acc[mt][nt][r];
                size_t vrow = (size_t)((m >> 11) * 16 + (n >> 6)) * 64 + (n & 63);
                int ml = m & 2047;
                int mp = (ml & ~31) | (((ml >> 2) & 3) << 3) | (((ml >> 4) & 1) << 2);
                *reinterpret_cast<bf16x4*>(&Vt[vrow * S_ + mp]) = o4;
            }
    } else if (MODE == 0) {
        bf16_t* CoH  = (z == 0) ? Qp : Kp;
        float   scale = (z == 0) ? cs : 1.0f;
#pragma unroll
        for (int mt = 0; mt < 4; mt++)
#pragma unroll
            for (int nt = 0; nt < 4; nt++)
#pragma unroll
                for (int r = 0; r < 4; r++) {
                    int m = m0 + wm + mt * 16 + quad * 4 + r;
                    int n = n0 + wn + nt * 16 + l15;
                    CoH[(size_t)m * 1024 + n] = (bf16_t)(acc[mt][nt][r] * scale);
                }
    } else {
#pragma unroll
        for (int mt = 0; mt < 4; mt++)
#pragma unroll
            for (int nt = 0; nt < 4; nt++)
#pragma unroll
                for (int r = 0; r < 4; r++) {
                    int m = m0 + wm + mt * 16 + quad * 4 + r;
                    int n = n0 + wn + nt * 16 + l15;
                    Co[(size_t)m * 1024 + n] = acc[mt][nt][r];
                }
    }
}

// ---------------- fused masked attention ----------------
// QBLK=64 (4 waves x 16 q-rows), 2048 WGs, LPT batch order + head clustering.
// K/V double-buffered via swizzled-source global_load_lds (16B-slot XOR row&7,
// applied on the GLOBAL source address and on every LDS read).
// V^T arrives pre-permuted into A-frag k-order (see gemm_ring MODE0 z=2), so PV
// fragments are single contiguous b128 reads -- no b64 pairs, no repacking.
__global__ __launch_bounds__(256) void attn_fused(const bf16_t* __restrict__ Qp,
                                                  const bf16_t* __restrict__ Kp,
                                                  const bf16_t* __restrict__ Vt,
                                                  const int* __restrict__ vlen_p,
                                                  bf16_t* __restrict__ Out) {
    __shared__ bf16_t smem[4][64 * 64];   // [0]=K0 (+epilogue T), [1]=V0, [2]=K1 (+Q prologue), [3]=V1

    int tid  = threadIdx.x;
    int lane = tid & 63, w = tid >> 6;
    int l15  = lane & 15, quad = lane >> 4;

    // ---- LPT + XCD-clustered tile decode ----
    int nk[4], ord[4] = {0, 1, 2, 3};
#pragma unroll
    for (int i = 0; i < 4; i++) nk[i] = (vlen_p[i] + 63) >> 6;
#pragma unroll
    for (int i = 0; i < 3; i++)
#pragma unroll
        for (int j = 0; j < 3 - i; j++)
            if (nk[ord[j + 1]] > nk[ord[j]]) { int t = ord[j]; ord[j] = ord[j + 1]; ord[j + 1] = t; }

    int bid  = blockIdx.x;
    int b    = ord[bid >> 9];              // heaviest batch first in dispatch order
    int t    = bid & 511;
    int h    = (t & 7) * 2 + ((t >> 3) & 1);  // 2 heads per XCD slot -> K/V L2 locality
    int qblk = t >> 4;                        // 0..31
    int vlen = vlen_p[b];
    int nkb  = (vlen + 63) >> 6;

    const bf16_t* Qg = Qp + (size_t)(b * S_ + qblk * 64) * D_ + h * 64;
    const bf16_t* Kg = Kp + (size_t)b * S_ * D_ + h * 64;
    const bf16_t* Vg = Vt + (size_t)(b * 16 + h) * 64 * S_;

    // per-lane staging addresses (incremental; XOR source swizzle baked in)
    int r0 = tid >> 3, s0 = tid & 7;
    int sx = (s0 ^ (r0 & 7)) * 8;            // (r0+32)&7 == r0&7
    const bf16_t* kS0 = Kg + (size_t)r0 * D_ + sx;
    const bf16_t* kS1 = kS0 + (size_t)32 * D_;
    const bf16_t* vS0 = Vg + (size_t)r0 * S_ + sx;
    const bf16_t* vS1 = vS0 + (size_t)32 * S_;

    // prologue: Q -> smem[2], K0 -> smem[0], V0 -> smem[1]
    {
        const bf16_t* qS0 = Qg + (size_t)r0 * D_ + sx;
        async_cp16(qS0,                   smem[2] + tid * 8);
        async_cp16(qS0 + (size_t)32 * D_, smem[2] + tid * 8 + 2048);
        async_cp16(kS0, smem[0] + tid * 8);
        async_cp16(kS1, smem[0] + tid * 8 + 2048);
        async_cp16(vS0, smem[1] + tid * 8);
        async_cp16(vS1, smem[1] + tid * 8 + 2048);
    }
    __syncthreads();

    bf16x8 qf[2];
    {
        int row = w * 16 + l15, x = row & 7;
#pragma unroll
        for (int kk = 0; kk < 2; kk++)
            qf[kk] = *reinterpret_cast<const bf16x8*>(&smem[2][row * 64 + ((kk * 4 + quad) ^ x) * 8]);
    }
    __syncthreads();   // all waves done with Q before kb=0 prefetch overwrites smem[2]

    f32x4 o[4] = {};
    float l_st = 0.f;

    for (int kb = 0; kb < nkb; kb++) {
        int cur = kb & 1;
        if (kb + 1 < nkb) {
            int nxt = cur ^ 1;
            kS0 += (size_t)64 * D_; kS1 += (size_t)64 * D_;
            vS0 += 64;              vS1 += 64;
            async_cp16(kS0, smem[nxt * 2]     + tid * 8);
            async_cp16(kS1, smem[nxt * 2]     + tid * 8 + 2048);
            async_cp16(vS0, smem[nxt * 2 + 1] + tid * 8);
            async_cp16(vS1, smem[nxt * 2 + 1] + tid * 8 + 2048);
        }
        const bf16_t* Kc = smem[cur * 2];
        const bf16_t* Vc = smem[cur * 2 + 1];

        // St = K Q^T  (rows = k, cols = this wave's 16 q)
        f32x4 sc[4] = {};
#pragma unroll
        for (int nt = 0; nt < 4; nt++) {
            int row = nt * 16 + l15, x = row & 7;
#pragma unroll
            for (int kk = 0; kk < 2; kk++) {
                bf16x8 kf = *reinterpret_cast<const bf16x8*>(&Kc[row * 64 + ((kk * 4 + quad) ^ x) * 8]);
                sc[nt] = __builtin_amdgcn_mfma_f32_16x16x32_bf16(kf, qf[kk], sc[nt], 0, 0, 0);
            }
        }

        // max-free softmax: p = exp2(st), scale baked into Q projection
        bool partial = (vlen & 63) && (kb == nkb - 1);
        bf16x8 pf[2];
        float lacc = 0.f;
        if (!partial) {
#pragma unroll
            for (int nt = 0; nt < 4; nt++)
#pragma unroll
                for (int r = 0; r < 4; r++) {
                    float p = __builtin_exp2f(sc[nt][r]);
                    lacc += p;
                    pf[nt >> 1][(nt & 1) * 4 + r] = (bf16_t)p;
                }
        } else {
#pragma unroll
            for (int nt = 0; nt < 4; nt++)
#pragma unroll
                for (int r = 0; r < 4; r++) {
                    float p = __builtin_exp2f(sc[nt][r]);
                    if (kb * 64 + nt * 16 + quad * 4 + r >= vlen) p = 0.f;
                    lacc += p;
                    pf[nt >> 1][(nt & 1) * 4 + r] = (bf16_t)p;
                }
        }
        l_st += lacc;

        // O^T += V^T P^T ; V pre-permuted -> single b128 A-frag per (np,dt)
#pragma unroll
        for (int np = 0; np < 2; np++)
#pragma unroll
            for (int dt = 0; dt < 4; dt++) {
                int row = dt * 16 + l15, x = row & 7;
                bf16x8 vfr = *reinterpret_cast<const bf16x8*>(&Vc[row * 64 + ((np * 4 + quad) ^ x) * 8]);
                o[dt] = __builtin_amdgcn_mfma_f32_16x16x32_bf16(vfr, pf[np], o[dt], 0, 0, 0);
            }

        __syncthreads();  // drains prefetch vmcnt + guards cur-buffer reuse
    }

    float l = l_st;
    l += __shfl_xor(l, 16);
    l += __shfl_xor(l, 32);
    float inv = 1.0f / l;

    // epilogue: O^T -> swizzled T (reuse K0) -> coalesced row-major store
    bf16_t* T = smem[0];
    {
        int row = w * 16 + l15, x = row & 7;
#pragma unroll
        for (int dt = 0; dt < 4; dt++) {
            bf16x4 o4;
#pragma unroll
            for (int r = 0; r < 4; r++) o4[r] = (bf16_t)(o[dt][r] * inv);
            int slot = dt * 2 + (quad >> 1);
            *reinterpret_cast<bf16x4*>(&T[row * 64 + (slot ^ x) * 8 + (quad & 1) * 4]) = o4;
        }
    }
    __syncthreads();
    {
        int row = tid >> 2, ch = tid & 3, x = row & 7;
        size_t obase = (size_t)(b * S_ + qblk * 64 + row) * D_ + h * 64 + ch * 16;
        bf16x8 f0 = *reinterpret_cast<const bf16x8*>(&T[row * 64 + ((ch * 2)     ^ x) * 8]);
        bf16x8 f1 = *reinterpret_cast<const bf16x8*>(&T[row * 64 + ((ch * 2 + 1) ^ x) * 8]);
        *reinterpret_cast<bf16x8*>(&Out[obase])     = f0;
        *reinterpret_cast<bf16x8*>(&Out[obase + 8]) = f1;
    }
}

extern "C" void kernel_launch(void* const* d_in, const int* in_sizes, int n_in,
                              void* d_out, int out_size, void* d_ws, size_t ws_size,
                              hipStream_t stream) {
    const float* q  = (const float*)d_in[0];
    const float* k  = (const float*)d_in[1];
    const float* v  = (const float*)d_in[2];
    const int*   vl = (const int*)d_in[3];
    const float* Wq = (const float*)d_in[4];
    const float* Wk = (const float*)d_in[5];
    const float* Wv = (const float*)d_in[6];
    const float* Wo = (const float*)d_in[7];
    float* out = (float*)d_out;

    bf16_t* ws = (bf16_t*)d_ws;
    const size_t SD = (size_t)8192 * 1024;
    const size_t WW = (size_t)1024 * 1024;
    bf16_t* tmpB = ws + SD;        // attn output
    bf16_t* Qp   = ws + 2 * SD;
    bf16_t* Kp   = ws + 3 * SD;
    bf16_t* Vt   = ws + 4 * SD;    // per-head V^T, s pre-permuted to A-frag order
    bf16_t* Wqb  = ws + 5 * SD;
    bf16_t* Wkb  = Wqb + WW;
    bf16_t* Wvb  = Wqb + 2 * WW;
    bf16_t* Wob  = Wqb + 3 * WW;

    const float cs = 0.18033688f;  // (1/8)*log2(e) baked into Q projection
    dim3 blk(256);

    cast4_f32_bf16<<<dim3(1024, 4), blk, 0, stream>>>(Wq, Wk, Wv, Wo, Wqb, Wkb, Wvb, Wob, 262144);
    gemm_ring<0><<<dim3(1536), blk, 0, stream>>>(q, k, v, Wqb, Wkb, Wvb, Qp, Kp, Vt, cs,
                                                 nullptr, nullptr, nullptr);
    attn_fused<<<dim3(2048), blk, 0, stream>>>(Qp, Kp, Vt, vl, tmpB);
    gemm_ring<1><<<dim3(512), blk, 0, stream>>>(nullptr, nullptr, nullptr, nullptr, nullptr, nullptr,
                                                nullptr, nullptr, nullptr, 1.0f, tmpB, Wob, out);
}

// Round 5
// 331.362 us; speedup vs baseline: 1.0082x; 1.0082x over previous
//
#include <hip/hip_runtime.h>
#include <hip/hip_bf16.h>

using bf16_t = __bf16;
using bf16x8 = __attribute__((ext_vector_type(8))) __bf16;
using bf16x4 = __attribute__((ext_vector_type(4))) __bf16;
using f32x4  = __attribute__((ext_vector_type(4))) float;

#define S_  2048
#define D_  1024

typedef __attribute__((address_space(1))) unsigned int glb_u32;
typedef __attribute__((address_space(3))) unsigned int lds_u32;

__device__ __forceinline__ void async_cp16(const void* g, void* lds) {
    __builtin_amdgcn_global_load_lds(
        (glb_u32*)(unsigned long long)g,
        (lds_u32*)(unsigned int)(unsigned long long)lds,
        16, 0, 0);
}

// ---------------- weights f32 -> bf16 ----------------
__global__ __launch_bounds__(256) void cast4_f32_bf16(const float* __restrict__ a, const float* __restrict__ b,
                                                      const float* __restrict__ c, const float* __restrict__ dd,
                                                      bf16_t* __restrict__ oa, bf16_t* __restrict__ ob,
                                                      bf16_t* __restrict__ oc, bf16_t* __restrict__ od, int n4) {
    int i = blockIdx.x * 256 + threadIdx.x;
    if (i >= n4) return;
    const float* s; bf16_t* d;
    int w = blockIdx.y;
    if      (w == 0) { s = a;  d = oa; }
    else if (w == 1) { s = b;  d = ob; }
    else if (w == 2) { s = c;  d = oc; }
    else             { s = dd; d = od; }
    float4 f = reinterpret_cast<const float4*>(s)[i];
    bf16x4 o;
    o[0] = (bf16_t)f.x; o[1] = (bf16_t)f.y; o[2] = (bf16_t)f.z; o[3] = (bf16_t)f.w;
    reinterpret_cast<bf16x4*>(d)[i] = o;
}

// ---------------- fused QKV projection: 3 GEMMs, one dispatch ----------------
// Round-3 structure (best measured): A f32 reg-staged + cvt->bf16 (loads issued
// before MFMA, ds_write after), B bf16 via global_load_lds, double-buffer,
// one __syncthreads per K-step. 1536 WGs.
// NEW: bank-conflict-free LDS swizzle, key (row>>1)&3 on the 16B slot index
// (addr16 mod 8 = (row&1)*4 + slot^key covers all 8 classes -> 2-way = free).
// Applied on A's ds_write addr, B's global source addr, and all reads.
// z=2 (V) stores per-head V^T with each 32-wide s-block permuted into MFMA
// A-frag order: pos = q*8 + hi*4 + r for s = q*4 + hi*16 + r.
__global__ __launch_bounds__(256) void qkv_gemm(const float* __restrict__ qf,
                                                const float* __restrict__ kf,
                                                const float* __restrict__ vf,
                                                const bf16_t* __restrict__ Wqb,
                                                const bf16_t* __restrict__ Wkb,
                                                const bf16_t* __restrict__ Wvb,
                                                bf16_t* __restrict__ Qp,
                                                bf16_t* __restrict__ Kp,
                                                bf16_t* __restrict__ Vt,
                                                float cs) {
    __shared__ bf16_t As[2][128 * 32];
    __shared__ bf16_t Bs[2][128 * 32];
    const int K = 1024;
    int tid  = threadIdx.x;
    int lane = tid & 63;
    int w    = tid >> 6;
    int l15  = lane & 15, quad = lane >> 4;

    int bid = blockIdx.x;
    int xcd = bid & 7, idx = bid >> 3;     // 0..191
    int z   = idx >> 6;                    // 0..2
    int rem = idx & 63;
    int m0 = (xcd * 8 + (rem & 7)) * 128;
    int n0 = (rem >> 3) * 128;
    int wm = (w >> 1) * 64, wn = (w & 1) * 64;

    const float*  Af; const bf16_t* Bt;
    if      (z == 0) { Af = qf; Bt = Wqb; }
    else if (z == 1) { Af = kf; Bt = Wkb; }
    else             { Af = vf; Bt = Wvb; }
    float scale = (z == 0) ? cs : 1.0f;

    const float* Ag = Af + (size_t)(m0 + (tid >> 2)) * K + (tid & 3) * 8;

    // A LDS write offset with swizzle (row key (row>>1)&3; row+64 has same key)
    int arow = tid >> 2, aslot = tid & 3;
    int aoff = arow * 32 + ((aslot ^ ((arow >> 1) & 3)) * 8);

    // B staging: source-swizzled so LDS stays DMA-linear
    const bf16_t* bSrc[2]; bf16_t* bDst0[2], *bDst1[2];
#pragma unroll
    for (int j = 0; j < 2; j++) {
        int linear = j * 256 + tid;
        int row = linear >> 2, s = linear & 3;
        bSrc[j]  = Bt + (size_t)(n0 + row) * K + ((s ^ ((row >> 1) & 3)) * 8);
        bDst0[j] = &Bs[0][linear * 8];
        bDst1[j] = &Bs[1][linear * 8];
    }

    float4 a0, a1, a2, a3;
    auto loadA = [&](int k0) {
        const float* p = Ag + k0;
        a0 = *reinterpret_cast<const float4*>(p);
        a1 = *reinterpret_cast<const float4*>(p + 4);
        a2 = *reinterpret_cast<const float4*>(p + (size_t)64 * K);
        a3 = *reinterpret_cast<const float4*>(p + (size_t)64 * K + 4);
    };
    auto storeA = [&](bf16_t* dst) {
        bf16x8 o0, o1;
        o0[0] = (bf16_t)a0.x; o0[1] = (bf16_t)a0.y; o0[2] = (bf16_t)a0.z; o0[3] = (bf16_t)a0.w;
        o0[4] = (bf16_t)a1.x; o0[5] = (bf16_t)a1.y; o0[6] = (bf16_t)a1.z; o0[7] = (bf16_t)a1.w;
        o1[0] = (bf16_t)a2.x; o1[1] = (bf16_t)a2.y; o1[2] = (bf16_t)a2.z; o1[3] = (bf16_t)a2.w;
        o1[4] = (bf16_t)a3.x; o1[5] = (bf16_t)a3.y; o1[6] = (bf16_t)a3.z; o1[7] = (bf16_t)a3.w;
        *reinterpret_cast<bf16x8*>(dst + aoff)        = o0;
        *reinterpret_cast<bf16x8*>(dst + aoff + 2048) = o1;
    };

    f32x4 acc[4][4] = {};

    loadA(0);
    async_cp16(bSrc[0], bDst0[0]);
    async_cp16(bSrc[1], bDst0[1]);
    storeA(As[0]);
    __syncthreads();

    for (int k0 = 0; k0 < K; k0 += 32) {
        int cur = (k0 >> 5) & 1;
        bool more = (k0 + 32 < K);
        if (more) {
            int nxt = cur ^ 1;
            loadA(k0 + 32);
            async_cp16(bSrc[0] + k0 + 32, nxt ? bDst1[0] : bDst0[0]);
            async_cp16(bSrc[1] + k0 + 32, nxt ? bDst1[1] : bDst0[1]);
        }
        bf16x8 af[4], bfr[4];
#pragma unroll
        for (int t = 0; t < 4; t++) {
            int ra = wm + t * 16 + l15;
            int rb = wn + t * 16 + l15;
            af[t]  = *reinterpret_cast<const bf16x8*>(&As[cur][ra * 32 + ((quad ^ ((ra >> 1) & 3)) * 8)]);
            bfr[t] = *reinterpret_cast<const bf16x8*>(&Bs[cur][rb * 32 + ((quad ^ ((rb >> 1) & 3)) * 8)]);
        }
#pragma unroll
        for (int mt = 0; mt < 4; mt++)
#pragma unroll
            for (int nt = 0; nt < 4; nt++)
                acc[mt][nt] = __builtin_amdgcn_mfma_f32_16x16x32_bf16(af[mt], bfr[nt], acc[mt][nt], 0, 0, 0);
        if (more) storeA(As[cur ^ 1]);
        __syncthreads();
    }

    if (z == 2) {
#pragma unroll
        for (int mt = 0; mt < 4; mt++)
#pragma unroll
            for (int nt = 0; nt < 4; nt++) {
                int m = m0 + wm + mt * 16 + quad * 4;   // s-dim base (4 consecutive)
                int n = n0 + wn + nt * 16 + l15;        // d-dim
                bf16x4 o4;
#pragma unroll
                for (int r = 0; r < 4; r++) o4[r] = (bf16_t)acc[mt][nt][r];
                size_t vrow = (size_t)((m >> 11) * 16 + (n >> 6)) * 64 + (n & 63);
                int ml = m & 2047;
                int mp = (ml & ~31) | (((ml >> 2) & 3) << 3) | (((ml >> 4) & 1) << 2);
                *reinterpret_cast<bf16x4*>(&Vt[vrow * S_ + mp]) = o4;
            }
    } else {
        bf16_t* Co = (z == 0) ? Qp : Kp;
#pragma unroll
        for (int mt = 0; mt < 4; mt++)
#pragma unroll
            for (int nt = 0; nt < 4; nt++)
#pragma unroll
                for (int r = 0; r < 4; r++) {
                    int m = m0 + wm + mt * 16 + quad * 4 + r;
                    int n = n0 + wn + nt * 16 + l15;
                    Co[(size_t)m * 1024 + n] = (bf16_t)(acc[mt][nt][r] * scale);
                }
    }
}

// ---------------- output GEMM: 3-stage ring, counted vmcnt ----------------
// A,B bf16 via global_load_lds; vmcnt(4) leaves the next stage's loads in
// flight across the raw s_barrier (pattern validated in round 4).
// Swizzle key upgraded to (row>>1)&3 (2-way = free).
__global__ __launch_bounds__(256) void gemm_out(const bf16_t* __restrict__ A,
                                                const bf16_t* __restrict__ Bt,
                                                float* __restrict__ C) {
    __shared__ bf16_t As[3][128 * 32];
    __shared__ bf16_t Bs[3][128 * 32];
    const int K = 1024;
    int tid  = threadIdx.x;
    int lane = tid & 63;
    int w    = tid >> 6;
    int l15  = lane & 15, quad = lane >> 4;

    int bid = blockIdx.x;
    int xcd = bid & 7, idx = bid >> 3;
    int m0 = (xcd * 8 + (idx & 7)) * 128;
    int n0 = (idx >> 3) * 128;
    int wm = (w >> 1) * 64, wn = (w & 1) * 64;

    const bf16_t* aSrc[2]; const bf16_t* bSrc[2];
    int dOff[2];
#pragma unroll
    for (int j = 0; j < 2; j++) {
        int linear = j * 256 + tid;
        int row = linear >> 2, s = linear & 3;
        int sw = (s ^ ((row >> 1) & 3)) * 8;
        aSrc[j] = A  + (size_t)(m0 + row) * K + sw;
        bSrc[j] = Bt + (size_t)(n0 + row) * K + sw;
        dOff[j] = linear * 8;
    }

    auto stage = [&](int buf, int koff) {
#pragma unroll
        for (int j = 0; j < 2; j++) async_cp16(aSrc[j] + koff, &As[buf][dOff[j]]);
#pragma unroll
        for (int j = 0; j < 2; j++) async_cp16(bSrc[j] + koff, &Bs[buf][dOff[j]]);
    };

    f32x4 acc[4][4] = {};

    stage(0, 0);
    stage(1, 32);

    int cur = 0, nx2 = 2;
    for (int i = 0; i < 32; ++i) {
        if (i == 31) asm volatile("s_waitcnt vmcnt(0)" ::: "memory");
        else         asm volatile("s_waitcnt vmcnt(4)" ::: "memory");
        __builtin_amdgcn_s_barrier();
        if (i + 2 < 32) stage(nx2, (i + 2) * 32);

        bf16x8 af[4], bfr[4];
#pragma unroll
        for (int t = 0; t < 4; t++) {
            int ra = wm + t * 16 + l15;
            int rb = wn + t * 16 + l15;
            af[t]  = *reinterpret_cast<const bf16x8*>(&As[cur][ra * 32 + ((quad ^ ((ra >> 1) & 3)) * 8)]);
            bfr[t] = *reinterpret_cast<const bf16x8*>(&Bs[cur][rb * 32 + ((quad ^ ((rb >> 1) & 3)) * 8)]);
        }
#pragma unroll
        for (int mt = 0; mt < 4; mt++)
#pragma unroll
            for (int nt = 0; nt < 4; nt++)
                acc[mt][nt] = __builtin_amdgcn_mfma_f32_16x16x32_bf16(af[mt], bfr[nt], acc[mt][nt], 0, 0, 0);

        cur = (cur == 2) ? 0 : cur + 1;
        nx2 = (nx2 == 2) ? 0 : nx2 + 1;
    }

#pragma unroll
    for (int mt = 0; mt < 4; mt++)
#pragma unroll
        for (int nt = 0; nt < 4; nt++)
#pragma unroll
            for (int r = 0; r < 4; r++) {
                int m = m0 + wm + mt * 16 + quad * 4 + r;
                int n = n0 + wn + nt * 16 + l15;
                C[(size_t)m * 1024 + n] = acc[mt][nt][r];
            }
}

// ---------------- fused masked attention ----------------
// NEW: 3-stage K/V ring with counted vmcnt(4) + raw s_barrier -- the old
// per-iter __syncthreads drained the just-issued prefetch to vmcnt(0), paying
// a full L2 round-trip every iteration. Prefetch distance is now 2 iterations.
// Q lives in registers (2 direct b128 loads/lane), LDS = 6 x 8KB = 48KB ->
// 3 WG/CU. Stage index clamped to nkb-1 keeps the vmcnt count uniform
// (dummy re-loads of the last tile are never read). Ring safety: iter kb's
// barrier proves buffer (kb-1)%3 consumed before stage(kb+2) overwrites it;
// vmcnt(4) always leaves exactly the newest 4 loads (stage kb+1) in flight.
__global__ __launch_bounds__(256) void attn_fused(const bf16_t* __restrict__ Qp,
                                                  const bf16_t* __restrict__ Kp,
                                                  const bf16_t* __restrict__ Vt,
                                                  const int* __restrict__ vlen_p,
                                                  bf16_t* __restrict__ Out) {
    __shared__ bf16_t smem[6][64 * 64];   // [0..2] = K ring (+[0] epilogue T), [3..5] = V ring

    int tid  = threadIdx.x;
    int lane = tid & 63, w = tid >> 6;
    int l15  = lane & 15, quad = lane >> 4;

    // ---- LPT + XCD-clustered tile decode ----
    int nk[4], ord[4] = {0, 1, 2, 3};
#pragma unroll
    for (int i = 0; i < 4; i++) nk[i] = (vlen_p[i] + 63) >> 6;
#pragma unroll
    for (int i = 0; i < 3; i++)
#pragma unroll
        for (int j = 0; j < 3 - i; j++)
            if (nk[ord[j + 1]] > nk[ord[j]]) { int t = ord[j]; ord[j] = ord[j + 1]; ord[j + 1] = t; }

    int bid  = blockIdx.x;
    int b    = ord[bid >> 9];              // heaviest batch first in dispatch order
    int t    = bid & 511;
    int h    = (t & 7) * 2 + ((t >> 3) & 1);  // 2 heads per XCD slot -> K/V L2 locality
    int qblk = t >> 4;                        // 0..31
    int vlen = vlen_p[b];
    int nkb  = (vlen + 63) >> 6;

    const bf16_t* Kg = Kp + (size_t)b * S_ * D_ + h * 64;
    const bf16_t* Vg = Vt + (size_t)(b * 16 + h) * 64 * S_;

    // ---- Q straight to registers (one-time, 2 x b128 per lane) ----
    bf16x8 qf[2];
    {
        int qrow = w * 16 + l15;
        const bf16_t* qp = Qp + (size_t)(b * S_ + qblk * 64 + qrow) * D_ + h * 64 + quad * 8;
        qf[0] = *reinterpret_cast<const bf16x8*>(qp);
        qf[1] = *reinterpret_cast<const bf16x8*>(qp + 32);
    }

    // per-lane staging addresses (XOR source swizzle baked in)
    int r0 = tid >> 3, s0 = tid & 7;
    int sx = (s0 ^ (r0 & 7)) * 8;            // (r0+32)&7 == r0&7
    const bf16_t* kB = Kg + (size_t)r0 * D_ + sx;
    const bf16_t* vB = Vg + (size_t)r0 * S_ + sx;

    auto stage = [&](int slot, int tile) {
        const bf16_t* kp = kB + (size_t)tile * 64 * D_;
        const bf16_t* vp = vB + tile * 64;
        async_cp16(kp,                    smem[slot]     + tid * 8);
        async_cp16(kp + (size_t)32 * D_,  smem[slot]     + tid * 8 + 2048);
        async_cp16(vp,                    smem[3 + slot] + tid * 8);
        async_cp16(vp + (size_t)32 * S_,  smem[3 + slot] + tid * 8 + 2048);
    };

    stage(0, 0);
    stage(1, nkb > 1 ? 1 : 0);

    f32x4 o[4] = {};
    float l_st = 0.f;

    int cur = 0, nx2 = 2;
    for (int kb = 0; kb < nkb; kb++) {
        asm volatile("s_waitcnt vmcnt(4)" ::: "memory");
        __builtin_amdgcn_s_barrier();
        {
            int tnext = kb + 2 < nkb ? kb + 2 : nkb - 1;
            stage(nx2, tnext);   // dummy (clamped) stages keep the count uniform
        }
        const bf16_t* Kc = smem[cur];
        const bf16_t* Vc = smem[3 + cur];

        // St = K Q^T  (rows = k, cols = this wave's 16 q)
        f32x4 sc[4] = {};
#pragma unroll
        for (int nt = 0; nt < 4; nt++) {
            int row = nt * 16 + l15, x = row & 7;
#pragma unroll
            for (int kk = 0; kk < 2; kk++) {
                bf16x8 kf = *reinterpret_cast<const bf16x8*>(&Kc[row * 64 + ((kk * 4 + quad) ^ x) * 8]);
                sc[nt] = __builtin_amdgcn_mfma_f32_16x16x32_bf16(kf, qf[kk], sc[nt], 0, 0, 0);
            }
        }

        // max-free softmax: p = exp2(st), scale baked into Q projection
        bool partial = (vlen & 63) && (kb == nkb - 1);
        bf16x8 pf[2];
        float lacc = 0.f;
        if (!partial) {
#pragma unroll
            for (int nt = 0; nt < 4; nt++)
#pragma unroll
                for (int r = 0; r < 4; r++) {
                    float p = __builtin_exp2f(sc[nt][r]);
                    lacc += p;
                    pf[nt >> 1][(nt & 1) * 4 + r] = (bf16_t)p;
                }
        } else {
#pragma unroll
            for (int nt = 0; nt < 4; nt++)
#pragma unroll
                for (int r = 0; r < 4; r++) {
                    float p = __builtin_exp2f(sc[nt][r]);
                    if (kb * 64 + nt * 16 + quad * 4 + r >= vlen) p = 0.f;
                    lacc += p;
                    pf[nt >> 1][(nt & 1) * 4 + r] = (bf16_t)p;
                }
        }
        l_st += lacc;

        // O^T += V^T P^T ; V pre-permuted -> single b128 A-frag per (np,dt)
#pragma unroll
        for (int np = 0; np < 2; np++)
#pragma unroll
            for (int dt = 0; dt < 4; dt++) {
                int row = dt * 16 + l15, x = row & 7;
                bf16x8 vfr = *reinterpret_cast<const bf16x8*>(&Vc[row * 64 + ((np * 4 + quad) ^ x) * 8]);
                o[dt] = __builtin_amdgcn_mfma_f32_16x16x32_bf16(vfr, pf[np], o[dt], 0, 0, 0);
            }

        cur = (cur == 2) ? 0 : cur + 1;
        nx2 = (nx2 == 2) ? 0 : nx2 + 1;
    }

    float l = l_st;
    l += __shfl_xor(l, 16);
    l += __shfl_xor(l, 32);
    float inv = 1.0f / l;

    // epilogue: O^T -> swizzled T (reuse K ring slot 0) -> coalesced store
    // __syncthreads drains all in-flight (incl. dummy) stages before T writes.
    __syncthreads();
    bf16_t* T = smem[0];
    {
        int row = w * 16 + l15, x = row & 7;
#pragma unroll
        for (int dt = 0; dt < 4; dt++) {
            bf16x4 o4;
#pragma unroll
            for (int r = 0; r < 4; r++) o4[r] = (bf16_t)(o[dt][r] * inv);
            int slot = dt * 2 + (quad >> 1);
            *reinterpret_cast<bf16x4*>(&T[row * 64 + (slot ^ x) * 8 + (quad & 1) * 4]) = o4;
        }
    }
    __syncthreads();
    {
        int row = tid >> 2, ch = tid & 3, x = row & 7;
        size_t obase = (size_t)(b * S_ + qblk * 64 + row) * D_ + h * 64 + ch * 16;
        bf16x8 f0 = *reinterpret_cast<const bf16x8*>(&T[row * 64 + ((ch * 2)     ^ x) * 8]);
        bf16x8 f1 = *reinterpret_cast<const bf16x8*>(&T[row * 64 + ((ch * 2 + 1) ^ x) * 8]);
        *reinterpret_cast<bf16x8*>(&Out[obase])     = f0;
        *reinterpret_cast<bf16x8*>(&Out[obase + 8]) = f1;
    }
}

extern "C" void kernel_launch(void* const* d_in, const int* in_sizes, int n_in,
                              void* d_out, int out_size, void* d_ws, size_t ws_size,
                              hipStream_t stream) {
    const float* q  = (const float*)d_in[0];
    const float* k  = (const float*)d_in[1];
    const float* v  = (const float*)d_in[2];
    const int*   vl = (const int*)d_in[3];
    const float* Wq = (const float*)d_in[4];
    const float* Wk = (const float*)d_in[5];
    const float* Wv = (const float*)d_in[6];
    const float* Wo = (const float*)d_in[7];
    float* out = (float*)d_out;

    bf16_t* ws = (bf16_t*)d_ws;
    const size_t SD = (size_t)8192 * 1024;
    const size_t WW = (size_t)1024 * 1024;
    bf16_t* tmpB = ws + SD;        // attn output
    bf16_t* Qp   = ws + 2 * SD;
    bf16_t* Kp   = ws + 3 * SD;
    bf16_t* Vt   = ws + 4 * SD;    // per-head V^T, s pre-permuted to A-frag order
    bf16_t* Wqb  = ws + 5 * SD;
    bf16_t* Wkb  = Wqb + WW;
    bf16_t* Wvb  = Wqb + 2 * WW;
    bf16_t* Wob  = Wqb + 3 * WW;

    const float cs = 0.18033688f;  // (1/8)*log2(e) baked into Q projection
    dim3 blk(256);

    cast4_f32_bf16<<<dim3(1024, 4), blk, 0, stream>>>(Wq, Wk, Wv, Wo, Wqb, Wkb, Wvb, Wob, 262144);
    qkv_gemm<<<dim3(1536), blk, 0, stream>>>(q, k, v, Wqb, Wkb, Wvb, Qp, Kp, Vt, cs);
    attn_fused<<<dim3(2048), blk, 0, stream>>>(Qp, Kp, Vt, vl, tmpB);
    gemm_out<<<dim3(512), blk, 0, stream>>>(tmpB, Wob, out);
}

// Round 6
// 311.943 us; speedup vs baseline: 1.0710x; 1.0623x over previous
//
#include <hip/hip_runtime.h>
#include <hip/hip_bf16.h>

using bf16_t = __bf16;
using bf16x8 = __attribute__((ext_vector_type(8))) __bf16;
using bf16x4 = __attribute__((ext_vector_type(4))) __bf16;
using f32x4  = __attribute__((ext_vector_type(4))) float;

#define S_  2048
#define D_  1024

typedef __attribute__((address_space(1))) unsigned int glb_u32;
typedef __attribute__((address_space(3))) unsigned int lds_u32;

__device__ __forceinline__ void async_cp16(const void* g, void* lds) {
    __builtin_amdgcn_global_load_lds(
        (glb_u32*)(unsigned long long)g,
        (lds_u32*)(unsigned int)(unsigned long long)lds,
        16, 0, 0);
}

// ---------------- weights f32 -> bf16 ----------------
__global__ __launch_bounds__(256) void cast4_f32_bf16(const float* __restrict__ a, const float* __restrict__ b,
                                                      const float* __restrict__ c, const float* __restrict__ dd,
                                                      bf16_t* __restrict__ oa, bf16_t* __restrict__ ob,
                                                      bf16_t* __restrict__ oc, bf16_t* __restrict__ od, int n4) {
    int i = blockIdx.x * 256 + threadIdx.x;
    if (i >= n4) return;
    const float* s; bf16_t* d;
    int w = blockIdx.y;
    if      (w == 0) { s = a;  d = oa; }
    else if (w == 1) { s = b;  d = ob; }
    else if (w == 2) { s = c;  d = oc; }
    else             { s = dd; d = od; }
    float4 f = reinterpret_cast<const float4*>(s)[i];
    bf16x4 o;
    o[0] = (bf16_t)f.x; o[1] = (bf16_t)f.y; o[2] = (bf16_t)f.z; o[3] = (bf16_t)f.w;
    reinterpret_cast<bf16x4*>(d)[i] = o;
}

// ---------------- fused QKV projection: 3 GEMMs, one dispatch ----------------
// Counted-vmcnt pipeline (no __syncthreads in the K-loop -- __syncthreads drains
// vmcnt(0), waiting on the JUST-ISSUED prefetch regardless of depth; that was
// the structural stall of rounds 3/5).
//   A: f32 reg-staged depth-2 (even/odd float4 sets), cvt->bf16 at storeA.
//   B: 3-buffer LDS ring via global_load_lds (source-swizzled, DMA-linear dst).
// Per iter: issue A(i+2)+B(i+2) [6 VMEM], ds_read frags, 16 MFMA, storeA(A(i+1))
// [compiler drains A(i+1) via vmcnt(8), keeps newer 8 in flight], then
// s_waitcnt vmcnt(6) lgkmcnt(0) + raw s_barrier: newest stage's 6 loads stay in
// flight ACROSS the barrier; lgkmcnt(0) publishes storeA's ds_writes cross-wave.
// Tail keeps counts uniform with clamped dummy stages into consumed buffers.
// LDS 40KB -> 4 WG/CU (was 32KB but 2.25 WG/CU effective); launch_bounds(,4).
// z=2 (V) stores per-head V^T with each 32-wide s-block permuted into MFMA
// A-frag order: pos = q*8 + hi*4 + r for s = q*4 + hi*16 + r.
__global__ __launch_bounds__(256, 4) void qkv_gemm(const float* __restrict__ qf,
                                                   const float* __restrict__ kf,
                                                   const float* __restrict__ vf,
                                                   const bf16_t* __restrict__ Wqb,
                                                   const bf16_t* __restrict__ Wkb,
                                                   const bf16_t* __restrict__ Wvb,
                                                   bf16_t* __restrict__ Qp,
                                                   bf16_t* __restrict__ Kp,
                                                   bf16_t* __restrict__ Vt,
                                                   float cs) {
    __shared__ bf16_t As[2][128 * 32];
    __shared__ bf16_t Bs[3][128 * 32];
    const int K = 1024;
    int tid  = threadIdx.x;
    int lane = tid & 63;
    int w    = tid >> 6;
    int l15  = lane & 15, quad = lane >> 4;

    int bid = blockIdx.x;
    int xcd = bid & 7, idx = bid >> 3;     // 0..191
    int z   = idx >> 6;                    // 0..2
    int rem = idx & 63;
    int m0 = (xcd * 8 + (rem & 7)) * 128;
    int n0 = (rem >> 3) * 128;
    int wm = (w >> 1) * 64, wn = (w & 1) * 64;

    const float*  Af; const bf16_t* Bt;
    if      (z == 0) { Af = qf; Bt = Wqb; }
    else if (z == 1) { Af = kf; Bt = Wkb; }
    else             { Af = vf; Bt = Wvb; }
    float scale = (z == 0) ? cs : 1.0f;

    const float* Ag = Af + (size_t)(m0 + (tid >> 2)) * K + (tid & 3) * 8;

    // A LDS write offset with swizzle (row key (row>>1)&3; row+64 same key)
    int arow = tid >> 2, aslot = tid & 3;
    int aoff = arow * 32 + ((aslot ^ ((arow >> 1) & 3)) * 8);

    // B staging: source-swizzled so LDS stays DMA-linear
    const bf16_t* bSrc[2]; int bOff[2];
#pragma unroll
    for (int j = 0; j < 2; j++) {
        int linear = j * 256 + tid;
        int row = linear >> 2, s = linear & 3;
        bSrc[j] = Bt + (size_t)(n0 + row) * K + ((s ^ ((row >> 1) & 3)) * 8);
        bOff[j] = linear * 8;
    }

    float4 aE[4], aO[4];
    auto loadA = [&](float4* a, int k0) {
        const float* p = Ag + k0;
        a[0] = *reinterpret_cast<const float4*>(p);
        a[1] = *reinterpret_cast<const float4*>(p + 4);
        a[2] = *reinterpret_cast<const float4*>(p + (size_t)64 * K);
        a[3] = *reinterpret_cast<const float4*>(p + (size_t)64 * K + 4);
    };
    auto storeA = [&](bf16_t* dst, const float4* a) {
        bf16x8 o0, o1;
        o0[0] = (bf16_t)a[0].x; o0[1] = (bf16_t)a[0].y; o0[2] = (bf16_t)a[0].z; o0[3] = (bf16_t)a[0].w;
        o0[4] = (bf16_t)a[1].x; o0[5] = (bf16_t)a[1].y; o0[6] = (bf16_t)a[1].z; o0[7] = (bf16_t)a[1].w;
        o1[0] = (bf16_t)a[2].x; o1[1] = (bf16_t)a[2].y; o1[2] = (bf16_t)a[2].z; o1[3] = (bf16_t)a[2].w;
        o1[4] = (bf16_t)a[3].x; o1[5] = (bf16_t)a[3].y; o1[6] = (bf16_t)a[3].z; o1[7] = (bf16_t)a[3].w;
        *reinterpret_cast<bf16x8*>(dst + aoff)        = o0;
        *reinterpret_cast<bf16x8*>(dst + aoff + 2048) = o1;
    };
    auto stageB = [&](bf16_t* dst, int k0) {
        async_cp16(bSrc[0] + k0, dst + bOff[0]);
        async_cp16(bSrc[1] + k0, dst + bOff[1]);
    };

    f32x4 acc[4][4] = {};
    bf16_t *bRead = Bs[0], *bMid = Bs[1], *bStage = Bs[2];

    // prologue: tiles 0 and 1 in flight, tile 0's A committed to LDS
    loadA(aE, 0);
    stageB(Bs[0], 0);
    loadA(aO, 32);
    stageB(Bs[1], 32);
    storeA(As[0], aE);                 // compiler waits A(0) only (vmcnt(8))
    asm volatile("s_waitcnt vmcnt(6) lgkmcnt(0)" ::: "memory");  // B(0) landed; A(1),B(1) in flight
    __builtin_amdgcn_s_barrier();

#pragma unroll 2
    for (int i = 0; i < 32; ++i) {
        int k2 = (i + 2 < 32) ? (i + 2) * 32 : 992;    // clamped dummy keeps counts uniform
        float4* aNew = (i & 1) ? aO : aE;              // set (i+2)&1 == i&1 (freed by storeA @ i-1)
        loadA(aNew, k2);
        stageB(bStage, k2);

        const bf16_t* Ac = As[i & 1];
        bf16x8 af[4], bfr[4];
#pragma unroll
        for (int t = 0; t < 4; t++) {
            int ra = wm + t * 16 + l15;
            int rb = wn + t * 16 + l15;
            af[t]  = *reinterpret_cast<const bf16x8*>(&Ac[ra * 32 + ((quad ^ ((ra >> 1) & 3)) * 8)]);
            bfr[t] = *reinterpret_cast<const bf16x8*>(&bRead[rb * 32 + ((quad ^ ((rb >> 1) & 3)) * 8)]);
        }
#pragma unroll
        for (int mt = 0; mt < 4; mt++)
#pragma unroll
            for (int nt = 0; nt < 4; nt++)
                acc[mt][nt] = __builtin_amdgcn_mfma_f32_16x16x32_bf16(af[mt], bfr[nt], acc[mt][nt], 0, 0, 0);

        if (i + 1 < 32) storeA(As[(i + 1) & 1], (i & 1) ? aE : aO);   // commit A(i+1)

        bf16_t* t0 = bRead; bRead = bMid; bMid = bStage; bStage = t0;
        asm volatile("s_waitcnt vmcnt(6) lgkmcnt(0)" ::: "memory");   // drain B(i+1); keep stage(i+2) in flight
        __builtin_amdgcn_s_barrier();
    }

    if (z == 2) {
#pragma unroll
        for (int mt = 0; mt < 4; mt++)
#pragma unroll
            for (int nt = 0; nt < 4; nt++) {
                int m = m0 + wm + mt * 16 + quad * 4;   // s-dim base (4 consecutive)
                int n = n0 + wn + nt * 16 + l15;        // d-dim
                bf16x4 o4;
#pragma unroll
                for (int r = 0; r < 4; r++) o4[r] = (bf16_t)acc[mt][nt][r];
                size_t vrow = (size_t)((m >> 11) * 16 + (n >> 6)) * 64 + (n & 63);
                int ml = m & 2047;
                int mp = (ml & ~31) | (((ml >> 2) & 3) << 3) | (((ml >> 4) & 1) << 2);
                *reinterpret_cast<bf16x4*>(&Vt[vrow * S_ + mp]) = o4;
            }
    } else {
        bf16_t* Co = (z == 0) ? Qp : Kp;
#pragma unroll
        for (int mt = 0; mt < 4; mt++)
#pragma unroll
            for (int nt = 0; nt < 4; nt++)
#pragma unroll
                for (int r = 0; r < 4; r++) {
                    int m = m0 + wm + mt * 16 + quad * 4 + r;
                    int n = n0 + wn + nt * 16 + l15;
                    Co[(size_t)m * 1024 + n] = (bf16_t)(acc[mt][nt][r] * scale);
                }
    }
}

// ---------------- output GEMM: 3-stage ring, counted vmcnt ----------------
__global__ __launch_bounds__(256) void gemm_out(const bf16_t* __restrict__ A,
                                                const bf16_t* __restrict__ Bt,
                                                float* __restrict__ C) {
    __shared__ bf16_t As[3][128 * 32];
    __shared__ bf16_t Bs[3][128 * 32];
    const int K = 1024;
    int tid  = threadIdx.x;
    int lane = tid & 63;
    int w    = tid >> 6;
    int l15  = lane & 15, quad = lane >> 4;

    int bid = blockIdx.x;
    int xcd = bid & 7, idx = bid >> 3;
    int m0 = (xcd * 8 + (idx & 7)) * 128;
    int n0 = (idx >> 3) * 128;
    int wm = (w >> 1) * 64, wn = (w & 1) * 64;

    const bf16_t* aSrc[2]; const bf16_t* bSrc[2];
    int dOff[2];
#pragma unroll
    for (int j = 0; j < 2; j++) {
        int linear = j * 256 + tid;
        int row = linear >> 2, s = linear & 3;
        int sw = (s ^ ((row >> 1) & 3)) * 8;
        aSrc[j] = A  + (size_t)(m0 + row) * K + sw;
        bSrc[j] = Bt + (size_t)(n0 + row) * K + sw;
        dOff[j] = linear * 8;
    }

    auto stage = [&](int buf, int koff) {
#pragma unroll
        for (int j = 0; j < 2; j++) async_cp16(aSrc[j] + koff, &As[buf][dOff[j]]);
#pragma unroll
        for (int j = 0; j < 2; j++) async_cp16(bSrc[j] + koff, &Bs[buf][dOff[j]]);
    };

    f32x4 acc[4][4] = {};

    stage(0, 0);
    stage(1, 32);

    int cur = 0, nx2 = 2;
    for (int i = 0; i < 32; ++i) {
        if (i == 31) asm volatile("s_waitcnt vmcnt(0)" ::: "memory");
        else         asm volatile("s_waitcnt vmcnt(4)" ::: "memory");
        __builtin_amdgcn_s_barrier();
        if (i + 2 < 32) stage(nx2, (i + 2) * 32);

        bf16x8 af[4], bfr[4];
#pragma unroll
        for (int t = 0; t < 4; t++) {
            int ra = wm + t * 16 + l15;
            int rb = wn + t * 16 + l15;
            af[t]  = *reinterpret_cast<const bf16x8*>(&As[cur][ra * 32 + ((quad ^ ((ra >> 1) & 3)) * 8)]);
            bfr[t] = *reinterpret_cast<const bf16x8*>(&Bs[cur][rb * 32 + ((quad ^ ((rb >> 1) & 3)) * 8)]);
        }
#pragma unroll
        for (int mt = 0; mt < 4; mt++)
#pragma unroll
            for (int nt = 0; nt < 4; nt++)
                acc[mt][nt] = __builtin_amdgcn_mfma_f32_16x16x32_bf16(af[mt], bfr[nt], acc[mt][nt], 0, 0, 0);

        cur = (cur == 2) ? 0 : cur + 1;
        nx2 = (nx2 == 2) ? 0 : nx2 + 1;
    }

#pragma unroll
    for (int mt = 0; mt < 4; mt++)
#pragma unroll
        for (int nt = 0; nt < 4; nt++)
#pragma unroll
            for (int r = 0; r < 4; r++) {
                int m = m0 + wm + mt * 16 + quad * 4 + r;
                int n = n0 + wn + nt * 16 + l15;
                C[(size_t)m * 1024 + n] = acc[mt][nt][r];
            }
}

// ---------------- fused masked attention (measured-best 81us version) ----------------
// QBLK=64 (4 waves x 16 q-rows), 2048 WGs, LPT batch order + head clustering.
// K/V double-buffered via swizzled-source global_load_lds; V^T pre-permuted
// into A-frag k-order -> single b128 PV fragments. 32KB LDS -> 4 WG/CU.
__global__ __launch_bounds__(256) void attn_fused(const bf16_t* __restrict__ Qp,
                                                  const bf16_t* __restrict__ Kp,
                                                  const bf16_t* __restrict__ Vt,
                                                  const int* __restrict__ vlen_p,
                                                  bf16_t* __restrict__ Out) {
    __shared__ bf16_t smem[4][64 * 64];   // [0]=K0 (+epilogue T), [1]=V0, [2]=K1 (+Q prologue), [3]=V1

    int tid  = threadIdx.x;
    int lane = tid & 63, w = tid >> 6;
    int l15  = lane & 15, quad = lane >> 4;

    // ---- LPT + XCD-clustered tile decode ----
    int nk[4], ord[4] = {0, 1, 2, 3};
#pragma unroll
    for (int i = 0; i < 4; i++) nk[i] = (vlen_p[i] + 63) >> 6;
#pragma unroll
    for (int i = 0; i < 3; i++)
#pragma unroll
        for (int j = 0; j < 3 - i; j++)
            if (nk[ord[j + 1]] > nk[ord[j]]) { int t = ord[j]; ord[j] = ord[j + 1]; ord[j + 1] = t; }

    int bid  = blockIdx.x;
    int b    = ord[bid >> 9];              // heaviest batch first in dispatch order
    int t    = bid & 511;
    int h    = (t & 7) * 2 + ((t >> 3) & 1);  // 2 heads per XCD slot -> K/V L2 locality
    int qblk = t >> 4;                        // 0..31
    int vlen = vlen_p[b];
    int nkb  = (vlen + 63) >> 6;

    const bf16_t* Qg = Qp + (size_t)(b * S_ + qblk * 64) * D_ + h * 64;
    const bf16_t* Kg = Kp + (size_t)b * S_ * D_ + h * 64;
    const bf16_t* Vg = Vt + (size_t)(b * 16 + h) * 64 * S_;

    // per-lane staging addresses (incremental; XOR source swizzle baked in)
    int r0 = tid >> 3, s0 = tid & 7;
    int sx = (s0 ^ (r0 & 7)) * 8;            // (r0+32)&7 == r0&7
    const bf16_t* kS0 = Kg + (size_t)r0 * D_ + sx;
    const bf16_t* kS1 = kS0 + (size_t)32 * D_;
    const bf16_t* vS0 = Vg + (size_t)r0 * S_ + sx;
    const bf16_t* vS1 = vS0 + (size_t)32 * S_;

    // prologue: Q -> smem[2], K0 -> smem[0], V0 -> smem[1]
    {
        const bf16_t* qS0 = Qg + (size_t)r0 * D_ + sx;
        async_cp16(qS0,                   smem[2] + tid * 8);
        async_cp16(qS0 + (size_t)32 * D_, smem[2] + tid * 8 + 2048);
        async_cp16(kS0, smem[0] + tid * 8);
        async_cp16(kS1, smem[0] + tid * 8 + 2048);
        async_cp16(vS0, smem[1] + tid * 8);
        async_cp16(vS1, smem[1] + tid * 8 + 2048);
    }
    __syncthreads();

    bf16x8 qf[2];
    {
        int row = w * 16 + l15, x = row & 7;
#pragma unroll
        for (int kk = 0; kk < 2; kk++)
            qf[kk] = *reinterpret_cast<const bf16x8*>(&smem[2][row * 64 + ((kk * 4 + quad) ^ x) * 8]);
    }
    __syncthreads();   // all waves done with Q before kb=0 prefetch overwrites smem[2]

    f32x4 o[4] = {};
    float l_st = 0.f;

    for (int kb = 0; kb < nkb; kb++) {
        int cur = kb & 1;
        if (kb + 1 < nkb) {
            int nxt = cur ^ 1;
            kS0 += (size_t)64 * D_; kS1 += (size_t)64 * D_;
            vS0 += 64;              vS1 += 64;
            async_cp16(kS0, smem[nxt * 2]     + tid * 8);
            async_cp16(kS1, smem[nxt * 2]     + tid * 8 + 2048);
            async_cp16(vS0, smem[nxt * 2 + 1] + tid * 8);
            async_cp16(vS1, smem[nxt * 2 + 1] + tid * 8 + 2048);
        }
        const bf16_t* Kc = smem[cur * 2];
        const bf16_t* Vc = smem[cur * 2 + 1];

        // St = K Q^T  (rows = k, cols = this wave's 16 q)
        f32x4 sc[4] = {};
#pragma unroll
        for (int nt = 0; nt < 4; nt++) {
            int row = nt * 16 + l15, x = row & 7;
#pragma unroll
            for (int kk = 0; kk < 2; kk++) {
                bf16x8 kf = *reinterpret_cast<const bf16x8*>(&Kc[row * 64 + ((kk * 4 + quad) ^ x) * 8]);
                sc[nt] = __builtin_amdgcn_mfma_f32_16x16x32_bf16(kf, qf[kk], sc[nt], 0, 0, 0);
            }
        }

        // max-free softmax: p = exp2(st), scale baked into Q projection
        bool partial = (vlen & 63) && (kb == nkb - 1);
        bf16x8 pf[2];
        float lacc = 0.f;
        if (!partial) {
#pragma unroll
            for (int nt = 0; nt < 4; nt++)
#pragma unroll
                for (int r = 0; r < 4; r++) {
                    float p = __builtin_exp2f(sc[nt][r]);
                    lacc += p;
                    pf[nt >> 1][(nt & 1) * 4 + r] = (bf16_t)p;
                }
        } else {
#pragma unroll
            for (int nt = 0; nt < 4; nt++)
#pragma unroll
                for (int r = 0; r < 4; r++) {
                    float p = __builtin_exp2f(sc[nt][r]);
                    if (kb * 64 + nt * 16 + quad * 4 + r >= vlen) p = 0.f;
                    lacc += p;
                    pf[nt >> 1][(nt & 1) * 4 + r] = (bf16_t)p;
                }
        }
        l_st += lacc;

        // O^T += V^T P^T ; V pre-permuted -> single b128 A-frag per (np,dt)
#pragma unroll
        for (int np = 0; np < 2; np++)
#pragma unroll
            for (int dt = 0; dt < 4; dt++) {
                int row = dt * 16 + l15, x = row & 7;
                bf16x8 vfr = *reinterpret_cast<const bf16x8*>(&Vc[row * 64 + ((np * 4 + quad) ^ x) * 8]);
                o[dt] = __builtin_amdgcn_mfma_f32_16x16x32_bf16(vfr, pf[np], o[dt], 0, 0, 0);
            }

        __syncthreads();  // drains prefetch vmcnt + guards cur-buffer reuse
    }

    float l = l_st;
    l += __shfl_xor(l, 16);
    l += __shfl_xor(l, 32);
    float inv = 1.0f / l;

    // epilogue: O^T -> swizzled T (reuse K0) -> coalesced row-major store
    bf16_t* T = smem[0];
    {
        int row = w * 16 + l15, x = row & 7;
#pragma unroll
        for (int dt = 0; dt < 4; dt++) {
            bf16x4 o4;
#pragma unroll
            for (int r = 0; r < 4; r++) o4[r] = (bf16_t)(o[dt][r] * inv);
            int slot = dt * 2 + (quad >> 1);
            *reinterpret_cast<bf16x4*>(&T[row * 64 + (slot ^ x) * 8 + (quad & 1) * 4]) = o4;
        }
    }
    __syncthreads();
    {
        int row = tid >> 2, ch = tid & 3, x = row & 7;
        size_t obase = (size_t)(b * S_ + qblk * 64 + row) * D_ + h * 64 + ch * 16;
        bf16x8 f0 = *reinterpret_cast<const bf16x8*>(&T[row * 64 + ((ch * 2)     ^ x) * 8]);
        bf16x8 f1 = *reinterpret_cast<const bf16x8*>(&T[row * 64 + ((ch * 2 + 1) ^ x) * 8]);
        *reinterpret_cast<bf16x8*>(&Out[obase])     = f0;
        *reinterpret_cast<bf16x8*>(&Out[obase + 8]) = f1;
    }
}

extern "C" void kernel_launch(void* const* d_in, const int* in_sizes, int n_in,
                              void* d_out, int out_size, void* d_ws, size_t ws_size,
                              hipStream_t stream) {
    const float* q  = (const float*)d_in[0];
    const float* k  = (const float*)d_in[1];
    const float* v  = (const float*)d_in[2];
    const int*   vl = (const int*)d_in[3];
    const float* Wq = (const float*)d_in[4];
    const float* Wk = (const float*)d_in[5];
    const float* Wv = (const float*)d_in[6];
    const float* Wo = (const float*)d_in[7];
    float* out = (float*)d_out;

    bf16_t* ws = (bf16_t*)d_ws;
    const size_t SD = (size_t)8192 * 1024;
    const size_t WW = (size_t)1024 * 1024;
    bf16_t* tmpB = ws + SD;        // attn output
    bf16_t* Qp   = ws + 2 * SD;
    bf16_t* Kp   = ws + 3 * SD;
    bf16_t* Vt   = ws + 4 * SD;    // per-head V^T, s pre-permuted to A-frag order
    bf16_t* Wqb  = ws + 5 * SD;
    bf16_t* Wkb  = Wqb + WW;
    bf16_t* Wvb  = Wqb + 2 * WW;
    bf16_t* Wob  = Wqb + 3 * WW;

    const float cs = 0.18033688f;  // (1/8)*log2(e) baked into Q projection
    dim3 blk(256);

    cast4_f32_bf16<<<dim3(1024, 4), blk, 0, stream>>>(Wq, Wk, Wv, Wo, Wqb, Wkb, Wvb, Wob, 262144);
    qkv_gemm<<<dim3(1536), blk, 0, stream>>>(q, k, v, Wqb, Wkb, Wvb, Qp, Kp, Vt, cs);
    attn_fused<<<dim3(2048), blk, 0, stream>>>(Qp, Kp, Vt, vl, tmpB);
    gemm_out<<<dim3(512), blk, 0, stream>>>(tmpB, Wob, out);
}